// Round 11
// baseline (377.596 us; speedup 1.0000x reference)
//
#include <hip/hip_runtime.h>
#include <math.h>

namespace {

constexpr int Bn = 16, Tn = 512, Dn = 768, Sn = 4, Hn = 48, On = 48;
constexpr int Mn = Bn * Tn;          // 8192 (b,t) rows
constexpr int Gn = Sn * Hn;          // 192 (s,h) groups
constexpr int Nn = Gn * On;          // 9216 flat N (= flat W rows)
constexpr float EMISS_W = 0.5f;

// workspace layout (float offsets), then bf16 regions ~27 MB
constexpr size_t OFF_LP   = 0;
constexpr size_t OFF_LT   = 64;
constexpr size_t OFF_PT   = OFF_LT + Hn*Hn;
constexpr size_t OFF_EM   = OFF_PT + Hn*Hn;
constexpr size_t OFF_LEPP = OFF_EM + (size_t)Sn*Hn*On;   // [m][g] g = s*48+h (log partials)
constexpr size_t OFF_LA   = OFF_LEPP + (size_t)Mn*Gn;    // alpha probs (per-t scale)
constexpr size_t OFF_LB   = OFF_LA + (size_t)Mn*Hn;      // beta probs (per-t scale)
constexpr size_t OFF_RED  = OFF_LB + (size_t)Mn*Hn;      // per-(b,t) partials [8192]
constexpr size_t FLOATS_END = OFF_RED + (size_t)Mn;

typedef __attribute__((ext_vector_type(8))) short short8;
typedef __attribute__((ext_vector_type(4))) float f32x4;

__device__ inline float waveSum(float v){
#pragma unroll
  for (int o = 32; o; o >>= 1) v += __shfl_xor(v, o);
  return v;
}

__device__ inline unsigned short f2bf(float f){
  unsigned int u = __float_as_uint(f);
  u += 0x7FFFu + ((u >> 16) & 1u);   // round-to-nearest-even
  return (unsigned short)(u >> 16);
}

__device__ inline void gload_lds16(const void* g, void* l){
  __builtin_amdgcn_global_load_lds(
      (const __attribute__((address_space(1))) void*)g,
      (__attribute__((address_space(3))) void*)l, 16, 0, 0);
}

// -------- conversion (all blocks but last) + param preprocessing (last block) --
__global__ void convprep_kernel(const float* __restrict__ srcA, unsigned short* __restrict__ dstA,
                                int n4a,
                                const float* __restrict__ srcB, unsigned short* __restrict__ dstB,
                                int n4b,
                                const float* __restrict__ sp, const float* __restrict__ ut,
                                const float* __restrict__ ue, float* __restrict__ ws,
                                int nconv){
  const int tid = threadIdx.x;
  if ((int)blockIdx.x == nconv){
    // ---- prep ----
    float m = -INFINITY;
    for (int h = 0; h < Hn; ++h) m = fmaxf(m, sp[h]);
    float s = 0.f;
    for (int h = 0; h < Hn; ++h) s += __expf(sp[h] - m);
    float lse = m + __logf(s);
    if (tid < Hn) ws[OFF_LP + tid] = sp[tid] - lse;
    if (tid < Hn){
      const float* row = ut + tid * Hn;
      float mm = -INFINITY;
      for (int j = 0; j < Hn; ++j) mm = fmaxf(mm, row[j]);
      float ss = 0.f;
      for (int j = 0; j < Hn; ++j) ss += __expf(row[j] - mm);
      float l = mm + __logf(ss);
      for (int j = 0; j < Hn; ++j){
        float v = row[j] - l;
        ws[OFF_LT + tid*Hn + j] = v;
        ws[OFF_PT + tid*Hn + j] = __expf(v);
      }
    }
    for (int r = tid; r < Sn*Hn; r += blockDim.x){
      const float* row = ue + (size_t)r * On;
      float mm = -INFINITY;
      for (int o = 0; o < On; ++o) mm = fmaxf(mm, row[o]);
      float ss = 0.f;
      for (int o = 0; o < On; ++o) ss += __expf(row[o] - mm);
      float inv = 1.f/ss;
      for (int o = 0; o < On; ++o) ws[OFF_EM + (size_t)r*On + o] = __expf(row[o]-mm)*inv;
    }
    return;
  }
  // ---- conv ----
  int i = blockIdx.x * blockDim.x + tid;
  const float* s2; unsigned short* d; int k;
  if (i < n4a){ s2 = srcA; d = dstA; k = i; }
  else { k = i - n4a; if (k >= n4b) return; s2 = srcB; d = dstB; }
  float4 v = ((const float4*)s2)[k];
  ushort4 r;
  r.x = f2bf(v.x); r.y = f2bf(v.y); r.z = f2bf(v.z); r.w = f2bf(v.w);
  ((ushort4*)d)[k] = r;
}

// ---------------- bf16 MFMA GEMM + fused softmax/mix/obs-dot epilogue ----------
// R20: OCCUPANCY axis. All prior configs had <=8 waves/CU (2/SIMD) -- barrier
// -twinned, nothing above 40% utilized (MFMA 37, VALU 31, LDS ~23%, HBM 11%)
// = latency-bound with no independent work. R20: FOUR independent 4-wave
// blocks per CU (16 waves, 4/SIMD). BM=128, BN=96, BK=32, 24 K-tiles,
// double buffer = 28672 B LDS (5 blocks LDS-wise); __launch_bounds__(256,4)
// targets <=128 VGPR (tally ~105: acc 48 + frags 28 + addrs 11) -> 4 blocks.
// BK=32's 4-slot bank collapse (R16: 64B rows -> 4 chunk slots, conflicts
// 3.5x) fixed by PAIRED-LINE layout: rows r and r+HALF share a 128B line:
//   line L, slot s (8 slots): row = L + HALF*((s>>2)^((L>>2)&1)),
//   chunk = (s&3)^(L&3)   -> 8 slot positions, 2 lanes/slot (free, m136).
// Stage sources are per-lane CONSTANTS (precomputed; only kt*32 varies);
// read offsets are 7 precomputed lane constants -> near-zero loop VALU.
// R14 single-gate/tile (vmcnt(0)+barrier), slab swizzle, R7-style stride-97
// epilogue (64-row halves). Diagnostic: OccupancyPercent must rise ~2x.
constexpr int BM = 128, BN = 96, BK = 32;
constexpr int NKT = Dn / BK;         // 24 K-tiles
// LDS byte map: A[2] @ 0 (2x8192), B[2] @ 16384 (2x6144), total 28672.

__global__ __launch_bounds__(256, 4) void gemm_lep_kernel(
    const unsigned short* __restrict__ embB, const unsigned short* __restrict__ WB,
    const float* __restrict__ bm, const float* __restrict__ obs,
    float* __restrict__ ws){
  __shared__ __align__(16) char smem[28672];
  const int tid = threadIdx.x, lane = tid & 63, w = tid >> 6;   // w 0..3
  // XCD slab swizzle: 6144 blocks. XCD x owns m-quarter (x&3) x N-half (x>>2);
  // inner over m (16 m-tiles = 3.1MB A slab, L2-resident), outer over n.
  const int bid = blockIdx.y * (Mn/BM) + blockIdx.x;
  const int xcd = bid & 7, j_loc = bid >> 3;     // j_loc in [0,768)
  const int xm = xcd & 3, xn = xcd >> 2;
  const int mloc = j_loc & 15, nloc = j_loc >> 4; // 16 m-tiles, 48 n-panels
  const int m0 = (xm*16 + mloc) * BM;             // m-tile 0..63
  const int np = xn*48 + nloc;                    // N-panel 0..95
  const int N0 = np * BN;
  const int wm = w & 1, wn = w >> 1;           // 2 x 2 wave grid (64x48 tiles)
  const int lm = lane & 15, q = lane >> 4;

  // ---- precomputed read byte-offsets (paired-line layout) ----
  const int hb = (lm >> 2) & 1;
  const int sA = 4*(wm ^ hb) + (q ^ (lm & 3));
  const int sB = 4*(wn ^ hb) + (q ^ (lm & 3));
  int aRd[4], bRd[3];
#pragma unroll
  for (int i = 0; i < 4; ++i) aRd[i] = (i*16 + lm)*128 + sA*16;
#pragma unroll
  for (int j = 0; j < 3; ++j) bRd[j] = (j*16 + lm)*128 + sB*16;

  // ---- precomputed stage source element-offsets (lane constants) ----
  // A calls idx 0..7 (this wave: 2*w, 2*w+1); B calls idx 0..5 (w; w<2 also 4+w)
  const int Ll = lane >> 3, sl = lane & 7, s_hi = sl >> 2, s_lo = sl & 3;
  auto precA = [&](int idx)->unsigned{
    int L = idx*8 + Ll;
    int row = L + 64*(s_hi ^ ((L >> 2) & 1));
    int ch  = s_lo ^ (L & 3);
    return (unsigned)((m0 + row)*Dn + ch*8);
  };
  auto precB = [&](int idx)->unsigned{
    int L = idx*8 + Ll;
    int row = L + 48*(s_hi ^ ((L >> 2) & 1));
    int ch  = s_lo ^ (L & 3);
    return (unsigned)((N0 + row)*Dn + ch*8);
  };
  const unsigned soA0 = precA(2*w), soA1 = precA(2*w + 1);
  const unsigned soB0 = precB(w);
  const unsigned soB1 = (w < 2) ? precB(4 + w) : 0u;
  const int dA0 = (2*w)*1024, dA1 = (2*w + 1)*1024, dB0 = w*1024, dB1 = (4 + w)*1024;

  f32x4 acc[4][3];
#pragma unroll
  for (int i = 0; i < 4; ++i)
#pragma unroll
    for (int j = 0; j < 3; ++j) acc[i][j] = (f32x4){0.f,0.f,0.f,0.f};

  auto stage = [&](int kt){
    const unsigned kOff = (unsigned)kt * BK;
    char* Ad = smem + (kt & 1)*8192;
    char* Bd = smem + 16384 + (kt & 1)*6144;
    gload_lds16(embB + soA0 + kOff, Ad + dA0);
    gload_lds16(embB + soA1 + kOff, Ad + dA1);
    gload_lds16(WB + soB0 + kOff, Bd + dB0);
    if (w < 2) gload_lds16(WB + soB1 + kOff, Bd + dB1);
  };

  // prologue: stage tile 0; in-loop gate waits it
  stage(0);

  for (int kt = 0; kt < NKT; ++kt){
    // ---- single gate per tile: own stages landed, all waves past prev tile
    asm volatile("s_waitcnt vmcnt(0)" ::: "memory");
    asm volatile("s_barrier" ::: "memory");
    const char* Ab = smem + (kt & 1)*8192;
    const char* Bb = smem + 16384 + (kt & 1)*6144;
    short8 af[4], bf[3];
#pragma unroll
    for (int j = 0; j < 3; ++j) bf[j] = *(const short8*)(Bb + bRd[j]);
#pragma unroll
    for (int i = 0; i < 4; ++i) af[i] = *(const short8*)(Ab + aRd[i]);
    if (kt + 1 < NKT) stage(kt + 1);            // opposite buffer, race-safe
#pragma unroll
    for (int i = 0; i < 4; ++i)
#pragma unroll
      for (int j = 0; j < 3; ++j)
        acc[i][j] = __builtin_amdgcn_mfma_f32_16x16x32_bf16(af[i], bf[j], acc[i][j], 0, 0, 0);
  }

  // ---- epilogue: park C in 2 halves of 64 rows (stride 97) over dead
  //      staging + bias/em tables; fused softmax / mix / obs-dot / log.
  __syncthreads();   // all waves done with staging LDS
  float* Cp  = (float*)smem;                 // 64*97*4 = 24832 B
  float* ext = (float*)(smem + 24832);       // bias [0..95], em [96..191]
  if (tid < 96){
    ext[tid]      = bm[N0 + tid];
    ext[96 + tid] = ws[OFF_EM + N0 + tid];
  }
#pragma unroll
  for (int h = 0; h < 2; ++h){
    if (h) __syncthreads();
    if (wm == h){
#pragma unroll
      for (int i = 0; i < 4; ++i)
#pragma unroll
        for (int j = 0; j < 3; ++j){
          const int col = wn*48 + j*16 + lm;
#pragma unroll
          for (int r = 0; r < 4; ++r){
            const int rowl = i*16 + q*4 + r;
            Cp[rowl*97 + col] = acc[i][j][r];
          }
        }
    }
    __syncthreads();
    if (tid < 128){
      const int rowl = tid >> 1, grp = tid & 1;
      const int m = m0 + h*64 + rowl;
      const int g = np*2 + grp;                // global group 0..191
      const int s2 = g / Hn;
      const float* crow = Cp + rowl*97 + grp*48;
      const float* ob   = obs + ((size_t)m*Sn + s2)*On;
      const float* bi   = ext + grp*48;
      const float* em   = ext + 96 + grp*48;
      float Z = 0.f, pd = 0.f, eo = 0.f;
#pragma unroll
      for (int o = 0; o < On; ++o){
        float e = __expf(crow[o] + bi[o]);
        float obv = ob[o];
        Z += e;
        pd = fmaf(e, obv, pd);
        eo = fmaf(em[o], obv, eo);
      }
      ws[OFF_LEPP + (size_t)m*Gn + g] = __logf((1.f-EMISS_W)*eo + EMISS_W*(pd/Z));
    }
  }
}

// ---------------- forward/backward recursions: chunked with warm-up ----------
// Serial depth 40 (FBW warm-up + FBL chunk). Stages exp(sum of 4 lep
// partials) straight from OFF_LEPP (lep_reduce kernel deleted).
constexpr int FBW = 24;   // warm-up steps
constexpr int FBL = 16;   // chunk length

__global__ __launch_bounds__(64) void fb_kernel(float* __restrict__ ws){
  __shared__ __align__(16) float ldsE[(FBW+FBL)*48];   // exp(lep) window
  __shared__ __align__(16) float ring[2][64];
  const int lane = threadIdx.x;
  const int c    = blockIdx.x;
  const int b    = blockIdx.y;
  const bool fwd = blockIdx.z == 0;
  const bool act = lane < Hn;
  const int t0 = c*FBL, te = t0 + FBL - 1;

  float pt[Hn];
#pragma unroll
  for (int i = 0; i < Hn; ++i)
    pt[i] = act ? (fwd ? ws[OFF_PT + i*Hn + lane] : ws[OFF_PT + lane*Hn + i]) : 0.f;

  int row_lo, nrows, sA, sZ;
  bool exact;
  if (fwd){
    sA = t0 - FBW;
    exact = (sA < 1);
    row_lo = exact ? 0 : sA;
    if (exact) sA = 1;
    sZ = te;
    nrows = te - row_lo + 1;
  } else {
    int th = te + 1 + FBW;
    exact = (th > Tn - 2);
    sA = exact ? Tn - 2 : th - 1;
    sZ = t0;
    row_lo = t0;
    nrows = sA - t0 + 1;
  }

  // stage exp(lep) = exp(sum of 4 partials) from [m][192] layout
  {
    const float* src = ws + OFF_LEPP + ((size_t)b*Tn + row_lo)*Gn;
    int n4 = nrows * (Hn/4);
    for (int i = lane; i < n4; i += 64){
      int r = i / (Hn/4), h4 = i - r*(Hn/4);
      const float* p = src + (size_t)r*Gn + h4*4;
      float4 a = *(const float4*)(p);
      float4 b2 = *(const float4*)(p + Hn);
      float4 c2 = *(const float4*)(p + 2*Hn);
      float4 d2 = *(const float4*)(p + 3*Hn);
      float4 e;
      e.x = __expf(a.x + b2.x + c2.x + d2.x);
      e.y = __expf(a.y + b2.y + c2.y + d2.y);
      e.z = __expf(a.z + b2.z + c2.z + d2.z);
      e.w = __expf(a.w + b2.w + c2.w + d2.w);
      ((float4*)ldsE)[i] = e;
    }
  }
  __syncthreads();

  if (fwd){
    const size_t laF = OFF_LA + (size_t)b * Tn * Hn;
    float v;
    if (exact){
      v = act ? __expf(ws[OFF_LP + lane]) * ldsE[lane] : 0.f;   // alpha_0
      if (c == 0 && act) ws[laF + lane] = v;
    } else {
      v = act ? 1.f : 0.f;
    }
    if (act) ring[0][lane] = v;
    __syncthreads();
    int cur = 0;
    for (int t = sA; t <= sZ; ++t){
      float S = waveSum(v);
      const float* rp = ring[cur];
      float s0=0.f,s1=0.f,s2=0.f,s3=0.f;
#pragma unroll
      for (int i = 0; i < Hn; i += 4){
        float4 a = *(const float4*)(rp + i);
        s0 = fmaf(a.x, pt[i+0], s0); s1 = fmaf(a.y, pt[i+1], s1);
        s2 = fmaf(a.z, pt[i+2], s2); s3 = fmaf(a.w, pt[i+3], s3);
      }
      float sd = (s0+s1)+(s2+s3);
      float e = act ? ldsE[(t - row_lo)*Hn + lane] : 0.f;
      float vn = act ? e * sd * (1.f/S) : 0.f;
      cur ^= 1;
      if (act) ring[cur][lane] = vn;
      __syncthreads();
      if (act && t >= t0) ws[laF + (size_t)t*Hn + lane] = vn;
      v = vn;
    }
  } else {
    const size_t lbF = OFF_LB + (size_t)b * Tn * Hn;
    float v = act ? 1.f : 0.f;
    if (exact && c == (Tn/FBL - 1) && act) ws[lbF + (size_t)(Tn-1)*Hn + lane] = 1.f;
    int cur = 0;
    for (int t = sA; t >= sZ; --t){
      float e = act ? ldsE[(t - row_lo)*Hn + lane] : 0.f;
      float wv = e * v;
      if (act) ring[cur][lane] = wv;
      float S = waveSum(wv);
      __syncthreads();
      const float* rp = ring[cur];
      float s0=0.f,s1=0.f,s2=0.f,s3=0.f;
#pragma unroll
      for (int j = 0; j < Hn; j += 4){
        float4 a = *(const float4*)(rp + j);
        s0 = fmaf(a.x, pt[j+0], s0); s1 = fmaf(a.y, pt[j+1], s1);
        s2 = fmaf(a.z, pt[j+2], s2); s3 = fmaf(a.w, pt[j+3], s3);
      }
      float vn = act ? ((s0+s1)+(s2+s3)) * (1.f/S) : 0.f;
      cur ^= 1;
      if (act && t <= te) ws[lbF + (size_t)t*Hn + lane] = vn;
      v = vn;
    }
  }
}

// -------- gamma / xi / masked accumulation (prob domain, no atomics) -----------
// One coalesced partial store per block; sum_kernel reduces. (R9's last-block
// counter pattern = 8192 serialized same-address atomics+fences = 165us. Never
// funnel per-block completion through one address on this chip.)
__global__ __launch_bounds__(256) void gamma_xi_kernel(
    const float* __restrict__ ws_c, float* __restrict__ ws,
    const int* __restrict__ seq_len){
  __shared__ float y_s[Hn], lap_s[Hn];
  __shared__ float red[8];
  const int tid = threadIdx.x;
  const int bid = blockIdx.x;
  const int b = bid >> 9, t = bid & (Tn-1);
  const int len = seq_len[b];
  int tb = t + (Tn - len); if (tb >= Tn) tb -= Tn;
  const size_t bt = (size_t)b*Tn + t;
  float lep = 0.f;
  if (tid < Hn){
    const float* lpp = ws_c + OFF_LEPP + bt*Gn + tid;
    lep = lpp[0] + lpp[Hn] + lpp[2*Hn] + lpp[3*Hn];
    float lb  = ws_c[OFF_LB + ((size_t)b*Tn + tb)*Hn + tid];
    y_s[tid] = __expf(lep) * lb;
    if (t >= 1) lap_s[tid] = ws_c[OFF_LA + (bt-1)*Hn + tid];
  }
  float emis_term = 0.f, prior_term = 0.f;
  if (tid < 64){
    int h = (tid < Hn) ? tid : 0;
    float la  = ws_c[OFF_LA + bt*Hn + h];
    float lb  = ws_c[OFF_LB + ((size_t)b*Tn + tb)*Hn + h];
    float lp  = ws_c[OFF_LP + h];
    float wgt = (tid < Hn) ? la*lb : 0.f;
    float Z = waveSum(wgt);
    float inv = 1.f / Z;
    emis_term  = waveSum(wgt * lep) * inv;
    prior_term = waveSum(wgt * lp) * inv;
  }
  __syncthreads();
  float tran_term = 0.f;
  if (t >= 1){
    float se = 0.f, st = 0.f;
#pragma unroll
    for (int k=0;k<9;++k){
      int e = tid + k*256;
      int i = e / Hn, j = e - i*Hn;
      float e2 = ws_c[OFF_PT + e] * lap_s[i] * y_s[j];
      se += e2;
      st = fmaf(e2, ws_c[OFF_LT + e], st);
    }
    se = waveSum(se);
    st = waveSum(st);
    const int wid = tid >> 6;
    if ((tid & 63) == 0){ red[wid] = se; red[4+wid] = st; }
    __syncthreads();
    if (tid == 0){
      float SE = red[0]+red[1]+red[2]+red[3];
      float ST = red[4]+red[5]+red[6]+red[7];
      tran_term = ST / SE;
    }
  }
  if (tid == 0){
    float tot = 0.f;
    if (t < len)            tot += emis_term;
    if (t == 0)             tot += prior_term;
    if (t >= 1 && t < len)  tot += tran_term;
    ws[OFF_RED + bid] = tot;
  }
}

// ---------------- final reduction: 8192 partials -> scalar ---------------------
__global__ __launch_bounds__(256) void sum_kernel(const float* __restrict__ ws,
                                                  float* __restrict__ out){
  __shared__ float red[4];
  const int tid = threadIdx.x;
  float s = 0.f;
  for (int i = tid; i < Mn; i += 256) s += ws[OFF_RED + i];
  s = waveSum(s);
  if ((tid & 63) == 0) red[tid >> 6] = s;
  __syncthreads();
  if (tid == 0) out[0] = (red[0]+red[1]+red[2]+red[3]) * (1.f / Bn);
}

} // namespace

extern "C" void kernel_launch(void* const* d_in, const int* in_sizes, int n_in,
                              void* d_out, int out_size, void* d_ws, size_t ws_size,
                              hipStream_t stream){
  const float* emb = (const float*)d_in[0];
  const float* obs = (const float*)d_in[1];
  const float* sp  = (const float*)d_in[2];
  const float* ut  = (const float*)d_in[3];
  const float* ue  = (const float*)d_in[4];
  const float* Wm  = (const float*)d_in[5];
  const float* bm  = (const float*)d_in[6];
  const int*   sl  = (const int*)d_in[7];
  float* ws  = (float*)d_ws;
  float* out = (float*)d_out;
  (void)in_sizes; (void)n_in; (void)ws_size; (void)out_size;

  unsigned short* embB = (unsigned short*)(ws + FLOATS_END);
  unsigned short* WB   = embB + (size_t)Mn * Dn;

  const int n4a = Mn*Dn/4, n4b = Nn*Dn/4;
  const int nconv = (n4a + n4b + 255)/256;
  convprep_kernel<<<nconv + 1, 256, 0, stream>>>(emb, embB, n4a, Wm, WB, n4b,
                                                 sp, ut, ue, ws, nconv);
  gemm_lep_kernel<<<dim3(Mn/BM, Nn/BN), 256, 0, stream>>>(embB, WB, bm, obs, ws);
  fb_kernel<<<dim3(Tn/FBL, Bn, 2), 64, 0, stream>>>(ws);
  gamma_xi_kernel<<<Bn*Tn, 256, 0, stream>>>(ws, ws, sl);
  sum_kernel<<<1, 256, 0, stream>>>(ws, out);
}

// Round 12
// 368.706 us; speedup vs baseline: 1.0241x; 1.0241x over previous
//
#include <hip/hip_runtime.h>
#include <math.h>

namespace {

constexpr int Bn = 16, Tn = 512, Dn = 768, Sn = 4, Hn = 48, On = 48;
constexpr int Mn = Bn * Tn;          // 8192 (b,t) rows
constexpr int Gn = Sn * Hn;          // 192 (s,h) groups
constexpr int Nn = Gn * On;          // 9216 flat N (= flat W rows)
constexpr float EMISS_W = 0.5f;

// workspace layout (float offsets), then bf16 regions ~27 MB
constexpr size_t OFF_LP   = 0;
constexpr size_t OFF_LT   = 64;
constexpr size_t OFF_PT   = OFF_LT + Hn*Hn;
constexpr size_t OFF_EM   = OFF_PT + Hn*Hn;
constexpr size_t OFF_LEPP = OFF_EM + (size_t)Sn*Hn*On;   // [m][g] g = s*48+h (log partials)
constexpr size_t OFF_LA   = OFF_LEPP + (size_t)Mn*Gn;    // alpha probs (per-t scale)
constexpr size_t OFF_LB   = OFF_LA + (size_t)Mn*Hn;      // beta probs (per-t scale)
constexpr size_t OFF_RED  = OFF_LB + (size_t)Mn*Hn;      // per-(b,t) partials [8192]
constexpr size_t FLOATS_END = OFF_RED + (size_t)Mn;

typedef __attribute__((ext_vector_type(8))) short short8;
typedef __attribute__((ext_vector_type(4))) float f32x4;

__device__ inline float waveSum(float v){
#pragma unroll
  for (int o = 32; o; o >>= 1) v += __shfl_xor(v, o);
  return v;
}

__device__ inline unsigned short f2bf(float f){
  unsigned int u = __float_as_uint(f);
  u += 0x7FFFu + ((u >> 16) & 1u);   // round-to-nearest-even
  return (unsigned short)(u >> 16);
}

__device__ inline void gload_lds16(const void* g, void* l){
  __builtin_amdgcn_global_load_lds(
      (const __attribute__((address_space(1))) void*)g,
      (__attribute__((address_space(3))) void*)l, 16, 0, 0);
}

// -------- conversion (all blocks but last) + param preprocessing (last block) --
__global__ void convprep_kernel(const float* __restrict__ srcA, unsigned short* __restrict__ dstA,
                                int n4a,
                                const float* __restrict__ srcB, unsigned short* __restrict__ dstB,
                                int n4b,
                                const float* __restrict__ sp, const float* __restrict__ ut,
                                const float* __restrict__ ue, float* __restrict__ ws,
                                int nconv){
  const int tid = threadIdx.x;
  if ((int)blockIdx.x == nconv){
    // ---- prep ----
    float m = -INFINITY;
    for (int h = 0; h < Hn; ++h) m = fmaxf(m, sp[h]);
    float s = 0.f;
    for (int h = 0; h < Hn; ++h) s += __expf(sp[h] - m);
    float lse = m + __logf(s);
    if (tid < Hn) ws[OFF_LP + tid] = sp[tid] - lse;
    if (tid < Hn){
      const float* row = ut + tid * Hn;
      float mm = -INFINITY;
      for (int j = 0; j < Hn; ++j) mm = fmaxf(mm, row[j]);
      float ss = 0.f;
      for (int j = 0; j < Hn; ++j) ss += __expf(row[j] - mm);
      float l = mm + __logf(ss);
      for (int j = 0; j < Hn; ++j){
        float v = row[j] - l;
        ws[OFF_LT + tid*Hn + j] = v;
        ws[OFF_PT + tid*Hn + j] = __expf(v);
      }
    }
    for (int r = tid; r < Sn*Hn; r += blockDim.x){
      const float* row = ue + (size_t)r * On;
      float mm = -INFINITY;
      for (int o = 0; o < On; ++o) mm = fmaxf(mm, row[o]);
      float ss = 0.f;
      for (int o = 0; o < On; ++o) ss += __expf(row[o] - mm);
      float inv = 1.f/ss;
      for (int o = 0; o < On; ++o) ws[OFF_EM + (size_t)r*On + o] = __expf(row[o]-mm)*inv;
    }
    return;
  }
  // ---- conv ----
  int i = blockIdx.x * blockDim.x + tid;
  const float* s2; unsigned short* d; int k;
  if (i < n4a){ s2 = srcA; d = dstA; k = i; }
  else { k = i - n4a; if (k >= n4b) return; s2 = srcB; d = dstB; }
  float4 v = ((const float4*)s2)[k];
  ushort4 r;
  r.x = f2bf(v.x); r.y = f2bf(v.y); r.z = f2bf(v.z); r.w = f2bf(v.w);
  ((ushort4*)d)[k] = r;
}

// ---------------- bf16 MFMA GEMM + fused softmax/mix/obs-dot epilogue ----------
// R21 = R20 minus the VGPR clamp. R20's occupancy test was confounded:
// __launch_bounds__(256,4) made hipcc clamp VGPR to 64 (empirical: arg=2 ->
// cap 128 across R13-R17; arg=4 -> cap 64), spilling the ~105-reg working
// set to scratch: WRITE_SIZE 8->136MB, FETCH +68MB, 243us. Fix: no
// min-waves arg -> compiler allocates ~105 <= 128 -> no spills, HW runs
// 4 waves/SIMD -> 4 independent 4-wave blocks/CU (16 waves; LDS 28672 B
// allows 5). This is the CLEAN occupancy test: all pipes <=40% utilized at
// 8 waves/CU across R13-R19 = latency-bound hypothesis. BM=128, BN=96,
// BK=32, 24 K-tiles, paired-line layout (correctness-verified in R20):
// rows r and r+HALF share a 128B line -> 8 chunk slots, R14-level banking.
// R14 single-gate/tile, slab swizzle, stride-97 epilogue.
constexpr int BM = 128, BN = 96, BK = 32;
constexpr int NKT = Dn / BK;         // 24 K-tiles
// LDS byte map: A[2] @ 0 (2x8192), B[2] @ 16384 (2x6144), total 28672.

__global__ __launch_bounds__(256) void gemm_lep_kernel(
    const unsigned short* __restrict__ embB, const unsigned short* __restrict__ WB,
    const float* __restrict__ bm, const float* __restrict__ obs,
    float* __restrict__ ws){
  __shared__ __align__(16) char smem[28672];
  const int tid = threadIdx.x, lane = tid & 63, w = tid >> 6;   // w 0..3
  // XCD slab swizzle: 6144 blocks. XCD x owns m-quarter (x&3) x N-half (x>>2);
  // inner over m (16 m-tiles = 3.1MB A slab, L2-resident), outer over n.
  const int bid = blockIdx.y * (Mn/BM) + blockIdx.x;
  const int xcd = bid & 7, j_loc = bid >> 3;     // j_loc in [0,768)
  const int xm = xcd & 3, xn = xcd >> 2;
  const int mloc = j_loc & 15, nloc = j_loc >> 4; // 16 m-tiles, 48 n-panels
  const int m0 = (xm*16 + mloc) * BM;             // m-tile 0..63
  const int np = xn*48 + nloc;                    // N-panel 0..95
  const int N0 = np * BN;
  const int wm = w & 1, wn = w >> 1;           // 2 x 2 wave grid (64x48 tiles)
  const int lm = lane & 15, q = lane >> 4;

  // ---- precomputed read byte-offsets (paired-line layout) ----
  const int hb = (lm >> 2) & 1;
  const int sA = 4*(wm ^ hb) + (q ^ (lm & 3));
  const int sB = 4*(wn ^ hb) + (q ^ (lm & 3));
  int aRd[4], bRd[3];
#pragma unroll
  for (int i = 0; i < 4; ++i) aRd[i] = (i*16 + lm)*128 + sA*16;
#pragma unroll
  for (int j = 0; j < 3; ++j) bRd[j] = (j*16 + lm)*128 + sB*16;

  // ---- precomputed stage source element-offsets (lane constants) ----
  // A calls idx 0..7 (this wave: 2*w, 2*w+1); B calls idx 0..5 (w; w<2 also 4+w)
  const int Ll = lane >> 3, sl = lane & 7, s_hi = sl >> 2, s_lo = sl & 3;
  auto precA = [&](int idx)->unsigned{
    int L = idx*8 + Ll;
    int row = L + 64*(s_hi ^ ((L >> 2) & 1));
    int ch  = s_lo ^ (L & 3);
    return (unsigned)((m0 + row)*Dn + ch*8);
  };
  auto precB = [&](int idx)->unsigned{
    int L = idx*8 + Ll;
    int row = L + 48*(s_hi ^ ((L >> 2) & 1));
    int ch  = s_lo ^ (L & 3);
    return (unsigned)((N0 + row)*Dn + ch*8);
  };
  const unsigned soA0 = precA(2*w), soA1 = precA(2*w + 1);
  const unsigned soB0 = precB(w);
  const unsigned soB1 = (w < 2) ? precB(4 + w) : 0u;
  const int dA0 = (2*w)*1024, dA1 = (2*w + 1)*1024, dB0 = w*1024, dB1 = (4 + w)*1024;

  f32x4 acc[4][3];
#pragma unroll
  for (int i = 0; i < 4; ++i)
#pragma unroll
    for (int j = 0; j < 3; ++j) acc[i][j] = (f32x4){0.f,0.f,0.f,0.f};

  auto stage = [&](int kt){
    const unsigned kOff = (unsigned)kt * BK;
    char* Ad = smem + (kt & 1)*8192;
    char* Bd = smem + 16384 + (kt & 1)*6144;
    gload_lds16(embB + soA0 + kOff, Ad + dA0);
    gload_lds16(embB + soA1 + kOff, Ad + dA1);
    gload_lds16(WB + soB0 + kOff, Bd + dB0);
    if (w < 2) gload_lds16(WB + soB1 + kOff, Bd + dB1);
  };

  // prologue: stage tile 0; in-loop gate waits it
  stage(0);

  for (int kt = 0; kt < NKT; ++kt){
    // ---- single gate per tile: own stages landed, all waves past prev tile
    asm volatile("s_waitcnt vmcnt(0)" ::: "memory");
    asm volatile("s_barrier" ::: "memory");
    const char* Ab = smem + (kt & 1)*8192;
    const char* Bb = smem + 16384 + (kt & 1)*6144;
    short8 af[4], bf[3];
#pragma unroll
    for (int j = 0; j < 3; ++j) bf[j] = *(const short8*)(Bb + bRd[j]);
#pragma unroll
    for (int i = 0; i < 4; ++i) af[i] = *(const short8*)(Ab + aRd[i]);
    if (kt + 1 < NKT) stage(kt + 1);            // opposite buffer, race-safe
#pragma unroll
    for (int i = 0; i < 4; ++i)
#pragma unroll
      for (int j = 0; j < 3; ++j)
        acc[i][j] = __builtin_amdgcn_mfma_f32_16x16x32_bf16(af[i], bf[j], acc[i][j], 0, 0, 0);
  }

  // ---- epilogue: park C in 2 halves of 64 rows (stride 97) over dead
  //      staging + bias/em tables; fused softmax / mix / obs-dot / log.
  __syncthreads();   // all waves done with staging LDS
  float* Cp  = (float*)smem;                 // 64*97*4 = 24832 B
  float* ext = (float*)(smem + 24832);       // bias [0..95], em [96..191]
  if (tid < 96){
    ext[tid]      = bm[N0 + tid];
    ext[96 + tid] = ws[OFF_EM + N0 + tid];
  }
#pragma unroll
  for (int h = 0; h < 2; ++h){
    if (h) __syncthreads();
    if (wm == h){
#pragma unroll
      for (int i = 0; i < 4; ++i)
#pragma unroll
        for (int j = 0; j < 3; ++j){
          const int col = wn*48 + j*16 + lm;
#pragma unroll
          for (int r = 0; r < 4; ++r){
            const int rowl = i*16 + q*4 + r;
            Cp[rowl*97 + col] = acc[i][j][r];
          }
        }
    }
    __syncthreads();
    if (tid < 128){
      const int rowl = tid >> 1, grp = tid & 1;
      const int m = m0 + h*64 + rowl;
      const int g = np*2 + grp;                // global group 0..191
      const int s2 = g / Hn;
      const float* crow = Cp + rowl*97 + grp*48;
      const float* ob   = obs + ((size_t)m*Sn + s2)*On;
      const float* bi   = ext + grp*48;
      const float* em   = ext + 96 + grp*48;
      float Z = 0.f, pd = 0.f, eo = 0.f;
#pragma unroll
      for (int o = 0; o < On; ++o){
        float e = __expf(crow[o] + bi[o]);
        float obv = ob[o];
        Z += e;
        pd = fmaf(e, obv, pd);
        eo = fmaf(em[o], obv, eo);
      }
      ws[OFF_LEPP + (size_t)m*Gn + g] = __logf((1.f-EMISS_W)*eo + EMISS_W*(pd/Z));
    }
  }
}

// ---------------- forward/backward recursions: chunked with warm-up ----------
// Serial depth 40 (FBW warm-up + FBL chunk). Stages exp(sum of 4 lep
// partials) straight from OFF_LEPP (lep_reduce kernel deleted).
constexpr int FBW = 24;   // warm-up steps
constexpr int FBL = 16;   // chunk length

__global__ __launch_bounds__(64) void fb_kernel(float* __restrict__ ws){
  __shared__ __align__(16) float ldsE[(FBW+FBL)*48];   // exp(lep) window
  __shared__ __align__(16) float ring[2][64];
  const int lane = threadIdx.x;
  const int c    = blockIdx.x;
  const int b    = blockIdx.y;
  const bool fwd = blockIdx.z == 0;
  const bool act = lane < Hn;
  const int t0 = c*FBL, te = t0 + FBL - 1;

  float pt[Hn];
#pragma unroll
  for (int i = 0; i < Hn; ++i)
    pt[i] = act ? (fwd ? ws[OFF_PT + i*Hn + lane] : ws[OFF_PT + lane*Hn + i]) : 0.f;

  int row_lo, nrows, sA, sZ;
  bool exact;
  if (fwd){
    sA = t0 - FBW;
    exact = (sA < 1);
    row_lo = exact ? 0 : sA;
    if (exact) sA = 1;
    sZ = te;
    nrows = te - row_lo + 1;
  } else {
    int th = te + 1 + FBW;
    exact = (th > Tn - 2);
    sA = exact ? Tn - 2 : th - 1;
    sZ = t0;
    row_lo = t0;
    nrows = sA - t0 + 1;
  }

  // stage exp(lep) = exp(sum of 4 partials) from [m][192] layout
  {
    const float* src = ws + OFF_LEPP + ((size_t)b*Tn + row_lo)*Gn;
    int n4 = nrows * (Hn/4);
    for (int i = lane; i < n4; i += 64){
      int r = i / (Hn/4), h4 = i - r*(Hn/4);
      const float* p = src + (size_t)r*Gn + h4*4;
      float4 a = *(const float4*)(p);
      float4 b2 = *(const float4*)(p + Hn);
      float4 c2 = *(const float4*)(p + 2*Hn);
      float4 d2 = *(const float4*)(p + 3*Hn);
      float4 e;
      e.x = __expf(a.x + b2.x + c2.x + d2.x);
      e.y = __expf(a.y + b2.y + c2.y + d2.y);
      e.z = __expf(a.z + b2.z + c2.z + d2.z);
      e.w = __expf(a.w + b2.w + c2.w + d2.w);
      ((float4*)ldsE)[i] = e;
    }
  }
  __syncthreads();

  if (fwd){
    const size_t laF = OFF_LA + (size_t)b * Tn * Hn;
    float v;
    if (exact){
      v = act ? __expf(ws[OFF_LP + lane]) * ldsE[lane] : 0.f;   // alpha_0
      if (c == 0 && act) ws[laF + lane] = v;
    } else {
      v = act ? 1.f : 0.f;
    }
    if (act) ring[0][lane] = v;
    __syncthreads();
    int cur = 0;
    for (int t = sA; t <= sZ; ++t){
      float S = waveSum(v);
      const float* rp = ring[cur];
      float s0=0.f,s1=0.f,s2=0.f,s3=0.f;
#pragma unroll
      for (int i = 0; i < Hn; i += 4){
        float4 a = *(const float4*)(rp + i);
        s0 = fmaf(a.x, pt[i+0], s0); s1 = fmaf(a.y, pt[i+1], s1);
        s2 = fmaf(a.z, pt[i+2], s2); s3 = fmaf(a.w, pt[i+3], s3);
      }
      float sd = (s0+s1)+(s2+s3);
      float e = act ? ldsE[(t - row_lo)*Hn + lane] : 0.f;
      float vn = act ? e * sd * (1.f/S) : 0.f;
      cur ^= 1;
      if (act) ring[cur][lane] = vn;
      __syncthreads();
      if (act && t >= t0) ws[laF + (size_t)t*Hn + lane] = vn;
      v = vn;
    }
  } else {
    const size_t lbF = OFF_LB + (size_t)b * Tn * Hn;
    float v = act ? 1.f : 0.f;
    if (exact && c == (Tn/FBL - 1) && act) ws[lbF + (size_t)(Tn-1)*Hn + lane] = 1.f;
    int cur = 0;
    for (int t = sA; t >= sZ; --t){
      float e = act ? ldsE[(t - row_lo)*Hn + lane] : 0.f;
      float wv = e * v;
      if (act) ring[cur][lane] = wv;
      float S = waveSum(wv);
      __syncthreads();
      const float* rp = ring[cur];
      float s0=0.f,s1=0.f,s2=0.f,s3=0.f;
#pragma unroll
      for (int j = 0; j < Hn; j += 4){
        float4 a = *(const float4*)(rp + j);
        s0 = fmaf(a.x, pt[j+0], s0); s1 = fmaf(a.y, pt[j+1], s1);
        s2 = fmaf(a.z, pt[j+2], s2); s3 = fmaf(a.w, pt[j+3], s3);
      }
      float vn = act ? ((s0+s1)+(s2+s3)) * (1.f/S) : 0.f;
      cur ^= 1;
      if (act && t <= te) ws[lbF + (size_t)t*Hn + lane] = vn;
      v = vn;
    }
  }
}

// -------- gamma / xi / masked accumulation (prob domain, no atomics) -----------
// One coalesced partial store per block; sum_kernel reduces. (R9's last-block
// counter pattern = 8192 serialized same-address atomics+fences = 165us. Never
// funnel per-block completion through one address on this chip.)
__global__ __launch_bounds__(256) void gamma_xi_kernel(
    const float* __restrict__ ws_c, float* __restrict__ ws,
    const int* __restrict__ seq_len){
  __shared__ float y_s[Hn], lap_s[Hn];
  __shared__ float red[8];
  const int tid = threadIdx.x;
  const int bid = blockIdx.x;
  const int b = bid >> 9, t = bid & (Tn-1);
  const int len = seq_len[b];
  int tb = t + (Tn - len); if (tb >= Tn) tb -= Tn;
  const size_t bt = (size_t)b*Tn + t;
  float lep = 0.f;
  if (tid < Hn){
    const float* lpp = ws_c + OFF_LEPP + bt*Gn + tid;
    lep = lpp[0] + lpp[Hn] + lpp[2*Hn] + lpp[3*Hn];
    float lb  = ws_c[OFF_LB + ((size_t)b*Tn + tb)*Hn + tid];
    y_s[tid] = __expf(lep) * lb;
    if (t >= 1) lap_s[tid] = ws_c[OFF_LA + (bt-1)*Hn + tid];
  }
  float emis_term = 0.f, prior_term = 0.f;
  if (tid < 64){
    int h = (tid < Hn) ? tid : 0;
    float la  = ws_c[OFF_LA + bt*Hn + h];
    float lb  = ws_c[OFF_LB + ((size_t)b*Tn + tb)*Hn + h];
    float lp  = ws_c[OFF_LP + h];
    float wgt = (tid < Hn) ? la*lb : 0.f;
    float Z = waveSum(wgt);
    float inv = 1.f / Z;
    emis_term  = waveSum(wgt * lep) * inv;
    prior_term = waveSum(wgt * lp) * inv;
  }
  __syncthreads();
  float tran_term = 0.f;
  if (t >= 1){
    float se = 0.f, st = 0.f;
#pragma unroll
    for (int k=0;k<9;++k){
      int e = tid + k*256;
      int i = e / Hn, j = e - i*Hn;
      float e2 = ws_c[OFF_PT + e] * lap_s[i] * y_s[j];
      se += e2;
      st = fmaf(e2, ws_c[OFF_LT + e], st);
    }
    se = waveSum(se);
    st = waveSum(st);
    const int wid = tid >> 6;
    if ((tid & 63) == 0){ red[wid] = se; red[4+wid] = st; }
    __syncthreads();
    if (tid == 0){
      float SE = red[0]+red[1]+red[2]+red[3];
      float ST = red[4]+red[5]+red[6]+red[7];
      tran_term = ST / SE;
    }
  }
  if (tid == 0){
    float tot = 0.f;
    if (t < len)            tot += emis_term;
    if (t == 0)             tot += prior_term;
    if (t >= 1 && t < len)  tot += tran_term;
    ws[OFF_RED + bid] = tot;
  }
}

// ---------------- final reduction: 8192 partials -> scalar ---------------------
__global__ __launch_bounds__(256) void sum_kernel(const float* __restrict__ ws,
                                                  float* __restrict__ out){
  __shared__ float red[4];
  const int tid = threadIdx.x;
  float s = 0.f;
  for (int i = tid; i < Mn; i += 256) s += ws[OFF_RED + i];
  s = waveSum(s);
  if ((tid & 63) == 0) red[tid >> 6] = s;
  __syncthreads();
  if (tid == 0) out[0] = (red[0]+red[1]+red[2]+red[3]) * (1.f / Bn);
}

} // namespace

extern "C" void kernel_launch(void* const* d_in, const int* in_sizes, int n_in,
                              void* d_out, int out_size, void* d_ws, size_t ws_size,
                              hipStream_t stream){
  const float* emb = (const float*)d_in[0];
  const float* obs = (const float*)d_in[1];
  const float* sp  = (const float*)d_in[2];
  const float* ut  = (const float*)d_in[3];
  const float* ue  = (const float*)d_in[4];
  const float* Wm  = (const float*)d_in[5];
  const float* bm  = (const float*)d_in[6];
  const int*   sl  = (const int*)d_in[7];
  float* ws  = (float*)d_ws;
  float* out = (float*)d_out;
  (void)in_sizes; (void)n_in; (void)ws_size; (void)out_size;

  unsigned short* embB = (unsigned short*)(ws + FLOATS_END);
  unsigned short* WB   = embB + (size_t)Mn * Dn;

  const int n4a = Mn*Dn/4, n4b = Nn*Dn/4;
  const int nconv = (n4a + n4b + 255)/256;
  convprep_kernel<<<nconv + 1, 256, 0, stream>>>(emb, embB, n4a, Wm, WB, n4b,
                                                 sp, ut, ue, ws, nconv);
  gemm_lep_kernel<<<dim3(Mn/BM, Nn/BN), 256, 0, stream>>>(embB, WB, bm, obs, ws);
  fb_kernel<<<dim3(Tn/FBL, Bn, 2), 64, 0, stream>>>(ws);
  gamma_xi_kernel<<<Bn*Tn, 256, 0, stream>>>(ws, ws, sl);
  sum_kernel<<<1, 256, 0, stream>>>(ws, out);
}

// Round 13
// 296.015 us; speedup vs baseline: 1.2756x; 1.2456x over previous
//
#include <hip/hip_runtime.h>
#include <math.h>

namespace {

constexpr int Bn = 16, Tn = 512, Dn = 768, Sn = 4, Hn = 48, On = 48;
constexpr int Mn = Bn * Tn;          // 8192 (b,t) rows
constexpr int Gn = Sn * Hn;          // 192 (s,h) groups
constexpr int Nn = Gn * On;          // 9216 flat N (= flat W rows)
constexpr float EMISS_W = 0.5f;

// workspace layout (float offsets), then bf16 regions ~27 MB
constexpr size_t OFF_LP   = 0;
constexpr size_t OFF_LT   = 64;
constexpr size_t OFF_PT   = OFF_LT + Hn*Hn;
constexpr size_t OFF_EM   = OFF_PT + Hn*Hn;
constexpr size_t OFF_LEPP = OFF_EM + (size_t)Sn*Hn*On;   // [m][g] g = s*48+h (log partials)
constexpr size_t OFF_LA   = OFF_LEPP + (size_t)Mn*Gn;    // alpha probs (per-t scale)
constexpr size_t OFF_LB   = OFF_LA + (size_t)Mn*Hn;      // beta probs (per-t scale)
constexpr size_t OFF_RED  = OFF_LB + (size_t)Mn*Hn;      // per-(b,t) partials [8192]
constexpr size_t FLOATS_END = OFF_RED + (size_t)Mn;

typedef __attribute__((ext_vector_type(8))) short short8;
typedef __attribute__((ext_vector_type(4))) float f32x4;

__device__ inline float waveSum(float v){
#pragma unroll
  for (int o = 32; o; o >>= 1) v += __shfl_xor(v, o);
  return v;
}

__device__ inline unsigned short f2bf(float f){
  unsigned int u = __float_as_uint(f);
  u += 0x7FFFu + ((u >> 16) & 1u);   // round-to-nearest-even
  return (unsigned short)(u >> 16);
}

__device__ inline void gload_lds16(const void* g, void* l){
  __builtin_amdgcn_global_load_lds(
      (const __attribute__((address_space(1))) void*)g,
      (__attribute__((address_space(3))) void*)l, 16, 0, 0);
}

// -------- conversion (all blocks but last) + param preprocessing (last block) --
__global__ void convprep_kernel(const float* __restrict__ srcA, unsigned short* __restrict__ dstA,
                                int n4a,
                                const float* __restrict__ srcB, unsigned short* __restrict__ dstB,
                                int n4b,
                                const float* __restrict__ sp, const float* __restrict__ ut,
                                const float* __restrict__ ue, float* __restrict__ ws,
                                int nconv){
  const int tid = threadIdx.x;
  if ((int)blockIdx.x == nconv){
    // ---- prep ----
    float m = -INFINITY;
    for (int h = 0; h < Hn; ++h) m = fmaxf(m, sp[h]);
    float s = 0.f;
    for (int h = 0; h < Hn; ++h) s += __expf(sp[h] - m);
    float lse = m + __logf(s);
    if (tid < Hn) ws[OFF_LP + tid] = sp[tid] - lse;
    if (tid < Hn){
      const float* row = ut + tid * Hn;
      float mm = -INFINITY;
      for (int j = 0; j < Hn; ++j) mm = fmaxf(mm, row[j]);
      float ss = 0.f;
      for (int j = 0; j < Hn; ++j) ss += __expf(row[j] - mm);
      float l = mm + __logf(ss);
      for (int j = 0; j < Hn; ++j){
        float v = row[j] - l;
        ws[OFF_LT + tid*Hn + j] = v;
        ws[OFF_PT + tid*Hn + j] = __expf(v);
      }
    }
    for (int r = tid; r < Sn*Hn; r += blockDim.x){
      const float* row = ue + (size_t)r * On;
      float mm = -INFINITY;
      for (int o = 0; o < On; ++o) mm = fmaxf(mm, row[o]);
      float ss = 0.f;
      for (int o = 0; o < On; ++o) ss += __expf(row[o] - mm);
      float inv = 1.f/ss;
      for (int o = 0; o < On; ++o) ws[OFF_EM + (size_t)r*On + o] = __expf(row[o]-mm)*inv;
    }
    return;
  }
  // ---- conv ----
  int i = blockIdx.x * blockDim.x + tid;
  const float* s2; unsigned short* d; int k;
  if (i < n4a){ s2 = srcA; d = dstA; k = i; }
  else { k = i - n4a; if (k >= n4b) return; s2 = srcB; d = dstB; }
  float4 v = ((const float4*)s2)[k];
  ushort4 r;
  r.x = f2bf(v.x); r.y = f2bf(v.y); r.z = f2bf(v.z); r.w = f2bf(v.w);
  ((ushort4*)d)[k] = r;
}

// ---------------- bf16 MFMA GEMM + fused softmax/mix/obs-dot epilogue ----------
// R22: 4-buffer BK=32, ONE barrier per TWO tiles. Corrected model: kernel is
// LDS-THROUGHPUT-bound (per CU-tile-pair: LDS reads+writes ~2820cy vs MFMA
// 1862cy); barrier-per-tile forces read-window/MFMA-window alternation (~60%
// LDS util = the 130us fixed point). Missing overlap is INTRA-WAVE CROSS-TILE:
// read tile t+1 frags while MFMAing tile t. Enabled by a 2-tile barrier-free
// window over 4 buffers: gate {vmcnt(0); s_barrier} per window (stages for
// t,t+1 issued a full window ~2300cy earlier -> no actual stall on
// L2-resident slabs), then reads(t), stage(t+2), reads(t+1), stage(t+3),
// MFMA(t), MFMA(t+1). Compiler emits counted lgkmcnt (m97-verified) ->
// tile-t+1 reads + stage writes are serviced during MFMA(t). Buffer hazard:
// writer of (t+2)%4 vs readers of (t-2)%4 separated by the gate barrier.
// BM=128 BN=192 BK=32, 4 waves (2x2, wave 64x96), LDS A 4x8K + B 4x12K
// = 81920 B -> 2 blocks/CU. Paired-line layout (R21 correctness+banking
// verified, conflicts 2.36M): rows r, r+HALF share a 128B line, 8 slots.
// Slab swizzle + R17's verified stride-193 epilogue unchanged.
constexpr int BM = 128, BN = 192, BK = 32;
constexpr int NKT = Dn / BK;         // 24 K-tiles
// LDS byte map: A[4] @ 0 (4x8192), B[4] @ 32768 (4x12288), total 81920.

__global__ __launch_bounds__(256) void gemm_lep_kernel(
    const unsigned short* __restrict__ embB, const unsigned short* __restrict__ WB,
    const float* __restrict__ bm, const float* __restrict__ obs,
    float* __restrict__ ws){
  __shared__ __align__(16) char smem[81920];   // staging; aliased by C-park+bias
  const int tid = threadIdx.x, lane = tid & 63, w = tid >> 6;   // w 0..3
  // XCD slab swizzle: 3072 blocks. XCD x owns m-quarter (x&3) x N-half (x>>2);
  // inner loop over m (16 m-tiles, A slab 3.1MB L2-resident), outer over n.
  const int bid = blockIdx.y * (Mn/BM) + blockIdx.x;
  const int xcd = bid & 7, j_loc = bid >> 3;     // j_loc in [0,384)
  const int xm = xcd & 3, xn = xcd >> 2;
  const int mloc = j_loc & 15, nloc = j_loc >> 4; // 16 m-tiles, 24 n-panels
  const int m0 = (xm*16 + mloc) * BM;             // m-tile 0..63
  const int by = xn*24 + nloc;                    // N-panel 0..47
  const int N0 = by * BN;
  const int wm = w & 1, wn = w >> 1;           // 2 x 2 wave grid (64x96 tiles)
  const int lm = lane & 15, q = lane >> 4;

  // ---- precomputed read byte-offsets (paired-line, verified R21) ----
  const int hb = (lm >> 2) & 1;
  const int sA = 4*(wm ^ hb) + (q ^ (lm & 3));
  const int sB = 4*(wn ^ hb) + (q ^ (lm & 3));
  int aRd[4], bRd[6];
#pragma unroll
  for (int i = 0; i < 4; ++i) aRd[i] = (i*16 + lm)*128 + sA*16;
#pragma unroll
  for (int j = 0; j < 6; ++j) bRd[j] = (j*16 + lm)*128 + sB*16;

  // ---- precomputed stage source element-offsets (lane constants) ----
  // A: 8 loads/tile (2/wave: idx w*2+i); B: 12 loads/tile (3/wave: idx w*3+i)
  const int Ll = lane >> 3, sl = lane & 7, s_hi = sl >> 2, s_lo = sl & 3;
  auto precA = [&](int idx)->unsigned{
    int L = idx*8 + Ll;                        // line 0..63
    int row = L + 64*(s_hi ^ ((L >> 2) & 1));
    int ch  = s_lo ^ (L & 3);
    return (unsigned)((m0 + row)*Dn + ch*8);
  };
  auto precB = [&](int idx)->unsigned{
    int L = idx*8 + Ll;                        // line 0..95
    int row = L + 96*(s_hi ^ ((L >> 2) & 1));
    int ch  = s_lo ^ (L & 3);
    return (unsigned)((N0 + row)*Dn + ch*8);
  };
  const unsigned soA0 = precA(2*w), soA1 = precA(2*w + 1);
  const unsigned soB0 = precB(3*w), soB1 = precB(3*w + 1), soB2 = precB(3*w + 2);
  const int dA0 = (2*w)*1024, dA1 = (2*w + 1)*1024;
  const int dB0 = (3*w)*1024, dB1 = (3*w + 1)*1024, dB2 = (3*w + 2)*1024;

  f32x4 acc[4][6];
#pragma unroll
  for (int i = 0; i < 4; ++i)
#pragma unroll
    for (int j = 0; j < 6; ++j) acc[i][j] = (f32x4){0.f,0.f,0.f,0.f};

  auto stage = [&](int kt){
    const unsigned kOff = (unsigned)kt * BK;
    char* Ad = smem + (kt & 3)*8192;
    char* Bd = smem + 32768 + (kt & 3)*12288;
    gload_lds16(embB + soA0 + kOff, Ad + dA0);
    gload_lds16(embB + soA1 + kOff, Ad + dA1);
    gload_lds16(WB + soB0 + kOff, Bd + dB0);
    gload_lds16(WB + soB1 + kOff, Bd + dB1);
    gload_lds16(WB + soB2 + kOff, Bd + dB2);
  };

  // prologue: stage tiles 0 and 1
  stage(0); stage(1);

  for (int kt = 0; kt < NKT; kt += 2){
    // ---- window gate: tiles kt,kt+1 landed (issued a full window ago);
    //      all waves past window kt-2 (their buffers now writable)
    asm volatile("s_waitcnt vmcnt(0)" ::: "memory");
    asm volatile("s_barrier" ::: "memory");
    const char* Ab0 = smem + (kt & 3)*8192;
    const char* Bb0 = smem + 32768 + (kt & 3)*12288;
    const char* Ab1 = smem + ((kt+1) & 3)*8192;
    const char* Bb1 = smem + 32768 + ((kt+1) & 3)*12288;

    short8 af[4], bf[6], ag[4], bg[6];
    // reads tile kt
#pragma unroll
    for (int j = 0; j < 6; ++j) bf[j] = *(const short8*)(Bb0 + bRd[j]);
#pragma unroll
    for (int i = 0; i < 4; ++i) af[i] = *(const short8*)(Ab0 + aRd[i]);
    if (kt + 2 < NKT) stage(kt + 2);
    // reads tile kt+1 (serviced during MFMA(kt) via counted lgkm)
#pragma unroll
    for (int j = 0; j < 6; ++j) bg[j] = *(const short8*)(Bb1 + bRd[j]);
#pragma unroll
    for (int i = 0; i < 4; ++i) ag[i] = *(const short8*)(Ab1 + aRd[i]);
    if (kt + 3 < NKT) stage(kt + 3);
    // MFMA tile kt
#pragma unroll
    for (int i = 0; i < 4; ++i)
#pragma unroll
      for (int j = 0; j < 6; ++j)
        acc[i][j] = __builtin_amdgcn_mfma_f32_16x16x32_bf16(af[i], bf[j], acc[i][j], 0, 0, 0);
    // MFMA tile kt+1
#pragma unroll
    for (int i = 0; i < 4; ++i)
#pragma unroll
      for (int j = 0; j < 6; ++j)
        acc[i][j] = __builtin_amdgcn_mfma_f32_16x16x32_bf16(ag[i], bg[j], acc[i][j], 0, 0, 0);
  }

  // ---- epilogue (R17-verified): park C (64 rows x stride 193) + bias/em
  //      tables over dead staging; fused softmax / mix / obs-dot / log.
  //      2 halves of 64 rows; 256 threads = 64 rows x 4 groups.
  __syncthreads();   // all waves done reading smem before C-park overwrites
  float* Cp  = (float*)smem;
  float* ext = (float*)(smem + 49408);   // bias [0..191], em [192..383]
  if (tid < 192){
    ext[tid]       = bm[N0 + tid];
    ext[192 + tid] = ws[OFF_EM + N0 + tid];
  }
#pragma unroll
  for (int h = 0; h < 2; ++h){
    if (h) __syncthreads();
    if (wm == h){
#pragma unroll
      for (int i = 0; i < 4; ++i)
#pragma unroll
        for (int j = 0; j < 6; ++j){
          const int col = wn*96 + j*16 + lm;
#pragma unroll
          for (int r = 0; r < 4; ++r){
            const int rowl = i*16 + q*4 + r;
            Cp[rowl*193 + col] = acc[i][j][r];
          }
        }
    }
    __syncthreads();
    {
      const int rowl = tid >> 2, grp = tid & 3;
      const int m = m0 + h*64 + rowl;
      const int g = by*4 + grp;
      const int s2 = g / Hn;                   // constant per block
      const float* crow = Cp + rowl*193 + grp*48;
      const float* ob   = obs + ((size_t)m*Sn + s2)*On;
      const float* bi   = ext + grp*48;
      const float* em   = ext + 192 + grp*48;
      float Z = 0.f, pd = 0.f, eo = 0.f;
#pragma unroll
      for (int o = 0; o < On; ++o){
        float e = __expf(crow[o] + bi[o]);
        float obv = ob[o];
        Z += e;
        pd = fmaf(e, obv, pd);
        eo = fmaf(em[o], obv, eo);
      }
      ws[OFF_LEPP + (size_t)m*Gn + g] = __logf((1.f-EMISS_W)*eo + EMISS_W*(pd/Z));
    }
  }
}

// ---------------- forward/backward recursions: chunked with warm-up ----------
// Serial depth 40 (FBW warm-up + FBL chunk). Stages exp(sum of 4 lep
// partials) straight from OFF_LEPP (lep_reduce kernel deleted).
constexpr int FBW = 24;   // warm-up steps
constexpr int FBL = 16;   // chunk length

__global__ __launch_bounds__(64) void fb_kernel(float* __restrict__ ws){
  __shared__ __align__(16) float ldsE[(FBW+FBL)*48];   // exp(lep) window
  __shared__ __align__(16) float ring[2][64];
  const int lane = threadIdx.x;
  const int c    = blockIdx.x;
  const int b    = blockIdx.y;
  const bool fwd = blockIdx.z == 0;
  const bool act = lane < Hn;
  const int t0 = c*FBL, te = t0 + FBL - 1;

  float pt[Hn];
#pragma unroll
  for (int i = 0; i < Hn; ++i)
    pt[i] = act ? (fwd ? ws[OFF_PT + i*Hn + lane] : ws[OFF_PT + lane*Hn + i]) : 0.f;

  int row_lo, nrows, sA, sZ;
  bool exact;
  if (fwd){
    sA = t0 - FBW;
    exact = (sA < 1);
    row_lo = exact ? 0 : sA;
    if (exact) sA = 1;
    sZ = te;
    nrows = te - row_lo + 1;
  } else {
    int th = te + 1 + FBW;
    exact = (th > Tn - 2);
    sA = exact ? Tn - 2 : th - 1;
    sZ = t0;
    row_lo = t0;
    nrows = sA - t0 + 1;
  }

  // stage exp(lep) = exp(sum of 4 partials) from [m][192] layout
  {
    const float* src = ws + OFF_LEPP + ((size_t)b*Tn + row_lo)*Gn;
    int n4 = nrows * (Hn/4);
    for (int i = lane; i < n4; i += 64){
      int r = i / (Hn/4), h4 = i - r*(Hn/4);
      const float* p = src + (size_t)r*Gn + h4*4;
      float4 a = *(const float4*)(p);
      float4 b2 = *(const float4*)(p + Hn);
      float4 c2 = *(const float4*)(p + 2*Hn);
      float4 d2 = *(const float4*)(p + 3*Hn);
      float4 e;
      e.x = __expf(a.x + b2.x + c2.x + d2.x);
      e.y = __expf(a.y + b2.y + c2.y + d2.y);
      e.z = __expf(a.z + b2.z + c2.z + d2.z);
      e.w = __expf(a.w + b2.w + c2.w + d2.w);
      ((float4*)ldsE)[i] = e;
    }
  }
  __syncthreads();

  if (fwd){
    const size_t laF = OFF_LA + (size_t)b * Tn * Hn;
    float v;
    if (exact){
      v = act ? __expf(ws[OFF_LP + lane]) * ldsE[lane] : 0.f;   // alpha_0
      if (c == 0 && act) ws[laF + lane] = v;
    } else {
      v = act ? 1.f : 0.f;
    }
    if (act) ring[0][lane] = v;
    __syncthreads();
    int cur = 0;
    for (int t = sA; t <= sZ; ++t){
      float S = waveSum(v);
      const float* rp = ring[cur];
      float s0=0.f,s1=0.f,s2=0.f,s3=0.f;
#pragma unroll
      for (int i = 0; i < Hn; i += 4){
        float4 a = *(const float4*)(rp + i);
        s0 = fmaf(a.x, pt[i+0], s0); s1 = fmaf(a.y, pt[i+1], s1);
        s2 = fmaf(a.z, pt[i+2], s2); s3 = fmaf(a.w, pt[i+3], s3);
      }
      float sd = (s0+s1)+(s2+s3);
      float e = act ? ldsE[(t - row_lo)*Hn + lane] : 0.f;
      float vn = act ? e * sd * (1.f/S) : 0.f;
      cur ^= 1;
      if (act) ring[cur][lane] = vn;
      __syncthreads();
      if (act && t >= t0) ws[laF + (size_t)t*Hn + lane] = vn;
      v = vn;
    }
  } else {
    const size_t lbF = OFF_LB + (size_t)b * Tn * Hn;
    float v = act ? 1.f : 0.f;
    if (exact && c == (Tn/FBL - 1) && act) ws[lbF + (size_t)(Tn-1)*Hn + lane] = 1.f;
    int cur = 0;
    for (int t = sA; t >= sZ; --t){
      float e = act ? ldsE[(t - row_lo)*Hn + lane] : 0.f;
      float wv = e * v;
      if (act) ring[cur][lane] = wv;
      float S = waveSum(wv);
      __syncthreads();
      const float* rp = ring[cur];
      float s0=0.f,s1=0.f,s2=0.f,s3=0.f;
#pragma unroll
      for (int j = 0; j < Hn; j += 4){
        float4 a = *(const float4*)(rp + j);
        s0 = fmaf(a.x, pt[j+0], s0); s1 = fmaf(a.y, pt[j+1], s1);
        s2 = fmaf(a.z, pt[j+2], s2); s3 = fmaf(a.w, pt[j+3], s3);
      }
      float vn = act ? ((s0+s1)+(s2+s3)) * (1.f/S) : 0.f;
      cur ^= 1;
      if (act && t <= te) ws[lbF + (size_t)t*Hn + lane] = vn;
      v = vn;
    }
  }
}

// -------- gamma / xi / masked accumulation (prob domain, no atomics) -----------
// One coalesced partial store per block; sum_kernel reduces. (R9's last-block
// counter pattern = 8192 serialized same-address atomics+fences = 165us. Never
// funnel per-block completion through one address on this chip.)
__global__ __launch_bounds__(256) void gamma_xi_kernel(
    const float* __restrict__ ws_c, float* __restrict__ ws,
    const int* __restrict__ seq_len){
  __shared__ float y_s[Hn], lap_s[Hn];
  __shared__ float red[8];
  const int tid = threadIdx.x;
  const int bid = blockIdx.x;
  const int b = bid >> 9, t = bid & (Tn-1);
  const int len = seq_len[b];
  int tb = t + (Tn - len); if (tb >= Tn) tb -= Tn;
  const size_t bt = (size_t)b*Tn + t;
  float lep = 0.f;
  if (tid < Hn){
    const float* lpp = ws_c + OFF_LEPP + bt*Gn + tid;
    lep = lpp[0] + lpp[Hn] + lpp[2*Hn] + lpp[3*Hn];
    float lb  = ws_c[OFF_LB + ((size_t)b*Tn + tb)*Hn + tid];
    y_s[tid] = __expf(lep) * lb;
    if (t >= 1) lap_s[tid] = ws_c[OFF_LA + (bt-1)*Hn + tid];
  }
  float emis_term = 0.f, prior_term = 0.f;
  if (tid < 64){
    int h = (tid < Hn) ? tid : 0;
    float la  = ws_c[OFF_LA + bt*Hn + h];
    float lb  = ws_c[OFF_LB + ((size_t)b*Tn + tb)*Hn + h];
    float lp  = ws_c[OFF_LP + h];
    float wgt = (tid < Hn) ? la*lb : 0.f;
    float Z = waveSum(wgt);
    float inv = 1.f / Z;
    emis_term  = waveSum(wgt * lep) * inv;
    prior_term = waveSum(wgt * lp) * inv;
  }
  __syncthreads();
  float tran_term = 0.f;
  if (t >= 1){
    float se = 0.f, st = 0.f;
#pragma unroll
    for (int k=0;k<9;++k){
      int e = tid + k*256;
      int i = e / Hn, j = e - i*Hn;
      float e2 = ws_c[OFF_PT + e] * lap_s[i] * y_s[j];
      se += e2;
      st = fmaf(e2, ws_c[OFF_LT + e], st);
    }
    se = waveSum(se);
    st = waveSum(st);
    const int wid = tid >> 6;
    if ((tid & 63) == 0){ red[wid] = se; red[4+wid] = st; }
    __syncthreads();
    if (tid == 0){
      float SE = red[0]+red[1]+red[2]+red[3];
      float ST = red[4]+red[5]+red[6]+red[7];
      tran_term = ST / SE;
    }
  }
  if (tid == 0){
    float tot = 0.f;
    if (t < len)            tot += emis_term;
    if (t == 0)             tot += prior_term;
    if (t >= 1 && t < len)  tot += tran_term;
    ws[OFF_RED + bid] = tot;
  }
}

// ---------------- final reduction: 8192 partials -> scalar ---------------------
__global__ __launch_bounds__(256) void sum_kernel(const float* __restrict__ ws,
                                                  float* __restrict__ out){
  __shared__ float red[4];
  const int tid = threadIdx.x;
  float s = 0.f;
  for (int i = tid; i < Mn; i += 256) s += ws[OFF_RED + i];
  s = waveSum(s);
  if ((tid & 63) == 0) red[tid >> 6] = s;
  __syncthreads();
  if (tid == 0) out[0] = (red[0]+red[1]+red[2]+red[3]) * (1.f / Bn);
}

} // namespace

extern "C" void kernel_launch(void* const* d_in, const int* in_sizes, int n_in,
                              void* d_out, int out_size, void* d_ws, size_t ws_size,
                              hipStream_t stream){
  const float* emb = (const float*)d_in[0];
  const float* obs = (const float*)d_in[1];
  const float* sp  = (const float*)d_in[2];
  const float* ut  = (const float*)d_in[3];
  const float* ue  = (const float*)d_in[4];
  const float* Wm  = (const float*)d_in[5];
  const float* bm  = (const float*)d_in[6];
  const int*   sl  = (const int*)d_in[7];
  float* ws  = (float*)d_ws;
  float* out = (float*)d_out;
  (void)in_sizes; (void)n_in; (void)ws_size; (void)out_size;

  unsigned short* embB = (unsigned short*)(ws + FLOATS_END);
  unsigned short* WB   = embB + (size_t)Mn * Dn;

  const int n4a = Mn*Dn/4, n4b = Nn*Dn/4;
  const int nconv = (n4a + n4b + 255)/256;
  convprep_kernel<<<nconv + 1, 256, 0, stream>>>(emb, embB, n4a, Wm, WB, n4b,
                                                 sp, ut, ue, ws, nconv);
  gemm_lep_kernel<<<dim3(Mn/BM, Nn/BN), 256, 0, stream>>>(embB, WB, bm, obs, ws);
  fb_kernel<<<dim3(Tn/FBL, Bn, 2), 64, 0, stream>>>(ws);
  gamma_xi_kernel<<<Bn*Tn, 256, 0, stream>>>(ws, ws, sl);
  sum_kernel<<<1, 256, 0, stream>>>(ws, out);
}

// Round 14
// 280.844 us; speedup vs baseline: 1.3445x; 1.0540x over previous
//
#include <hip/hip_runtime.h>
#include <math.h>

namespace {

constexpr int Bn = 16, Tn = 512, Dn = 768, Sn = 4, Hn = 48, On = 48;
constexpr int Mn = Bn * Tn;          // 8192 (b,t) rows
constexpr int Gn = Sn * Hn;          // 192 (s,h) groups
constexpr int Nn = Gn * On;          // 9216 flat N (= flat W rows)
constexpr float EMISS_W = 0.5f;

// workspace layout (float offsets), then bf16 regions ~27 MB
constexpr size_t OFF_LP   = 0;
constexpr size_t OFF_LT   = 64;
constexpr size_t OFF_PT   = OFF_LT + Hn*Hn;
constexpr size_t OFF_EM   = OFF_PT + Hn*Hn;
constexpr size_t OFF_LEPP = OFF_EM + (size_t)Sn*Hn*On;   // [m][g] g = s*48+h (log partials)
constexpr size_t OFF_LA   = OFF_LEPP + (size_t)Mn*Gn;    // alpha probs (per-t scale)
constexpr size_t OFF_LB   = OFF_LA + (size_t)Mn*Hn;      // beta probs (per-t scale)
constexpr size_t OFF_RED  = OFF_LB + (size_t)Mn*Hn;      // per-(b,t) partials [8192]
constexpr size_t FLOATS_END = OFF_RED + (size_t)Mn;

typedef __attribute__((ext_vector_type(8))) short short8;
typedef __attribute__((ext_vector_type(4))) float f32x4;

__device__ inline float waveSum(float v){
#pragma unroll
  for (int o = 32; o; o >>= 1) v += __shfl_xor(v, o);
  return v;
}

__device__ inline unsigned short f2bf(float f){
  unsigned int u = __float_as_uint(f);
  u += 0x7FFFu + ((u >> 16) & 1u);   // round-to-nearest-even
  return (unsigned short)(u >> 16);
}

__device__ inline void gload_lds16(const void* g, void* l){
  __builtin_amdgcn_global_load_lds(
      (const __attribute__((address_space(1))) void*)g,
      (__attribute__((address_space(3))) void*)l, 16, 0, 0);
}

// -------- conversion (all blocks but last) + param preprocessing (last block) --
__global__ void convprep_kernel(const float* __restrict__ srcA, unsigned short* __restrict__ dstA,
                                int n4a,
                                const float* __restrict__ srcB, unsigned short* __restrict__ dstB,
                                int n4b,
                                const float* __restrict__ sp, const float* __restrict__ ut,
                                const float* __restrict__ ue, float* __restrict__ ws,
                                int nconv){
  const int tid = threadIdx.x;
  if ((int)blockIdx.x == nconv){
    // ---- prep ----
    float m = -INFINITY;
    for (int h = 0; h < Hn; ++h) m = fmaxf(m, sp[h]);
    float s = 0.f;
    for (int h = 0; h < Hn; ++h) s += __expf(sp[h] - m);
    float lse = m + __logf(s);
    if (tid < Hn) ws[OFF_LP + tid] = sp[tid] - lse;
    if (tid < Hn){
      const float* row = ut + tid * Hn;
      float mm = -INFINITY;
      for (int j = 0; j < Hn; ++j) mm = fmaxf(mm, row[j]);
      float ss = 0.f;
      for (int j = 0; j < Hn; ++j) ss += __expf(row[j] - mm);
      float l = mm + __logf(ss);
      for (int j = 0; j < Hn; ++j){
        float v = row[j] - l;
        ws[OFF_LT + tid*Hn + j] = v;
        ws[OFF_PT + tid*Hn + j] = __expf(v);
      }
    }
    for (int r = tid; r < Sn*Hn; r += blockDim.x){
      const float* row = ue + (size_t)r * On;
      float mm = -INFINITY;
      for (int o = 0; o < On; ++o) mm = fmaxf(mm, row[o]);
      float ss = 0.f;
      for (int o = 0; o < On; ++o) ss += __expf(row[o] - mm);
      float inv = 1.f/ss;
      for (int o = 0; o < On; ++o) ws[OFF_EM + (size_t)r*On + o] = __expf(row[o]-mm)*inv;
    }
    return;
  }
  // ---- conv ----
  int i = blockIdx.x * blockDim.x + tid;
  const float* s2; unsigned short* d; int k;
  if (i < n4a){ s2 = srcA; d = dstA; k = i; }
  else { k = i - n4a; if (k >= n4b) return; s2 = srcB; d = dstB; }
  float4 v = ((const float4*)s2)[k];
  ushort4 r;
  r.x = f2bf(v.x); r.y = f2bf(v.y); r.z = f2bf(v.z); r.w = f2bf(v.w);
  ((ushort4*)d)[k] = r;
}

// ---------------- bf16 MFMA GEMM + fused softmax/mix/obs-dot epilogue ----------
// FINAL (champion revert = R19, best measured total 278.48us). Session
// fixed point: 7 structurally distinct schedules (1-gate, 4-phase, 2-phase
// counted-vmcnt, 2-tile window, stagger, setprio-ablation, interleave) all
// land at gemm 129-158us / MfmaUtil 31-41% -- LDS-read + MFMA windows
// serialize per CU and no HIP-level schedule breaks it. 256x192 tile,
// 8 waves (2Mx4N, wave 128x48), BK=64, double buffer 112KB (1 block/CU).
// 2 phases/tile, B-read-once: P1 = A i0-3 + all B -> 24 MFMA; P2 = A i4-7,
// B reused from regs -> 24 MFMA. Counted gates: tile gate vmcnt(2), mid
// gate vmcnt(5). setprio around MFMA. XCD slab swizzle (A slab 3.1MB/XCD
// L2-resident, FETCH ~110MB verified R11-R19).
constexpr int BM = 256, BN = 192, BK = 64;
constexpr int NKT = Dn / BK;         // 12 K-tiles
// LDS byte map: A[2] @ 0 (2x32768), B[2] @ 65536 (2x24576), total 114688.

__global__ __launch_bounds__(512, 1) void gemm_lep_kernel(
    const unsigned short* __restrict__ embB, const unsigned short* __restrict__ WB,
    const float* __restrict__ bm, const float* __restrict__ obs,
    float* __restrict__ ws){
  __shared__ __align__(16) char smem[114688];   // staging; aliased by C-park+bias
  const int tid = threadIdx.x, lane = tid & 63, w = tid >> 6;   // w 0..7
  // XCD slab swizzle: 1536 blocks. XCD x owns m-quarter (x&3) x N-half (x>>2);
  // inner loop over m (8 m-tiles of 256 rows = 3.1MB A slab, L2-resident).
  const int bid = blockIdx.y * (Mn/BM) + blockIdx.x;
  const int xcd = bid & 7, j_loc = bid >> 3;     // j_loc in [0,192)
  const int xm = xcd & 3, xn = xcd >> 2;
  const int mloc = j_loc & 7, nloc = j_loc >> 3; // 8 m-tiles, 24 n-panels
  const int m0 = (xm*8 + mloc) * BM;             // m-tile 0..31
  const int by = xn*24 + nloc;                   // N-panel 0..47
  const int N0 = by * BN;
  const int wm = w & 1, wn = w >> 1;           // 2 x 4 wave grid
  const int lm = lane & 15, q = lane >> 4;
  const int key = lm & 7;
  const int srow = lane >> 3, spc = lane & 7;
  const int aoff0 = (q ^ key) << 4;            // kk=0 chunk byte offset
  const int aoff1 = ((4 + q) ^ key) << 4;      // kk=1

  f32x4 acc[8][3];
#pragma unroll
  for (int i = 0; i < 8; ++i)
#pragma unroll
    for (int j = 0; j < 3; ++j) acc[i][j] = (f32x4){0.f,0.f,0.f,0.f};

  // A stages: region-1 (phase-1 rows: 0-63 & 128-191) = idx {w, 16+w};
  //           region-2 (phase-2 rows: 64-127 & 192-255) = idx {8+w, 24+w}.
  auto stageA = [&](int kt, int idx){
    const int row = idx*8 + srow;
    const int lc  = spc ^ (row & 7);
    gload_lds16(embB + (size_t)(m0+row)*Dn + kt*BK + lc*8,
                smem + (kt & 1)*32768 + idx*1024);
  };
  auto stageB = [&](int kt, int i){            // i = 0..2, idx 0..23
    const int idx = w*3 + i;
    const int row = idx*8 + srow;
    const int lc  = spc ^ (row & 7);
    gload_lds16(WB + (size_t)(N0+row)*Dn + kt*BK + lc*8,
                smem + 65536 + (kt & 1)*24576 + idx*1024);
  };

  // prologue: tile 0, region order [5 x r1, 2 x r2]
  stageA(0, w); stageA(0, 16 + w);
  stageB(0, 0); stageB(0, 1); stageB(0, 2);
  stageA(0, 8 + w); stageA(0, 24 + w);

  for (int kt = 0; kt < NKT; ++kt){
    const char* Ab = smem + (kt & 1)*32768;
    const char* Bb = smem + 65536 + (kt & 1)*24576;
    const int pf = kt + 1;
    const bool dopf = pf < NKT;

    // ---- tile gate: drain this tile's 5 region-1 loads (issued >=2 phases
    //      ago); keep its 2 A-p2 loads in flight
    asm volatile("s_waitcnt vmcnt(2)" ::: "memory");
    asm volatile("s_barrier" ::: "memory");

    // ---- P1: reads A i0-3 (both kk) + ALL B (both kk)
    short8 a0[4], a1[4], b0[3], b1[3];
#pragma unroll
    for (int j = 0; j < 3; ++j){
      const char* bp = Bb + (wn*48 + j*16 + lm)*128;
      b0[j] = *(const short8*)(bp + aoff0);
      b1[j] = *(const short8*)(bp + aoff1);
    }
#pragma unroll
    for (int i = 0; i < 4; ++i){
      const char* ap = Ab + (wm*128 + i*16 + lm)*128;
      a0[i] = *(const short8*)(ap + aoff0);
      a1[i] = *(const short8*)(ap + aoff1);
    }
    if (dopf){                                  // 5 region-1 stages for t+1
      stageA(pf, w); stageA(pf, 16 + w);
      stageB(pf, 0); stageB(pf, 1); stageB(pf, 2);
    }
    __builtin_amdgcn_s_setprio(1);
#pragma unroll
    for (int i = 0; i < 4; ++i)
#pragma unroll
      for (int j = 0; j < 3; ++j)
        acc[i][j] = __builtin_amdgcn_mfma_f32_16x16x32_bf16(a0[i], b0[j], acc[i][j], 0, 0, 0);
#pragma unroll
    for (int i = 0; i < 4; ++i)
#pragma unroll
      for (int j = 0; j < 3; ++j)
        acc[i][j] = __builtin_amdgcn_mfma_f32_16x16x32_bf16(a1[i], b1[j], acc[i][j], 0, 0, 0);
    __builtin_amdgcn_s_setprio(0);

    // ---- mid gate: drain this tile's 2 A-p2 loads (issued a full tile ago);
    //      keep t+1's 5 region-1 loads (just issued) in flight
    if (dopf) asm volatile("s_waitcnt vmcnt(5)" ::: "memory");
    else      asm volatile("s_waitcnt vmcnt(0)" ::: "memory");
    asm volatile("s_barrier" ::: "memory");

    // ---- P2: reads A i4-7 (both kk); B fragments reused from registers
    short8 a2[4], a3[4];
#pragma unroll
    for (int i = 0; i < 4; ++i){
      const char* ap = Ab + (wm*128 + 64 + i*16 + lm)*128;
      a2[i] = *(const short8*)(ap + aoff0);
      a3[i] = *(const short8*)(ap + aoff1);
    }
    if (dopf){ stageA(pf, 8 + w); stageA(pf, 24 + w); }  // 2 region-2 stages
    __builtin_amdgcn_s_setprio(1);
#pragma unroll
    for (int i = 0; i < 4; ++i)
#pragma unroll
      for (int j = 0; j < 3; ++j)
        acc[4+i][j] = __builtin_amdgcn_mfma_f32_16x16x32_bf16(a2[i], b0[j], acc[4+i][j], 0, 0, 0);
#pragma unroll
    for (int i = 0; i < 4; ++i)
#pragma unroll
      for (int j = 0; j < 3; ++j)
        acc[4+i][j] = __builtin_amdgcn_mfma_f32_16x16x32_bf16(a3[i], b1[j], acc[4+i][j], 0, 0, 0);
    __builtin_amdgcn_s_setprio(0);
  }

  // ---- epilogue: park C in 2 halves of 128 rows (stride 193) over dead
  //      staging + bias/em tables; fused softmax / mix / obs-dot / log.
  //      512 threads = 128 rows x 4 groups per half.
  __syncthreads();   // all waves done reading smem before C-park overwrites
  float* Cp  = (float*)smem;
  float* ext = (float*)(smem + 98816);   // bias [0..191], em [192..383]
  if (tid < 192){
    ext[tid]       = bm[N0 + tid];
    ext[192 + tid] = ws[OFF_EM + N0 + tid];
  }
#pragma unroll
  for (int h = 0; h < 2; ++h){
    if (h) __syncthreads();
    if (wm == h){
#pragma unroll
      for (int i = 0; i < 8; ++i)
#pragma unroll
        for (int j = 0; j < 3; ++j){
          const int col = wn*48 + j*16 + lm;
#pragma unroll
          for (int r = 0; r < 4; ++r){
            const int rowl = i*16 + q*4 + r;
            Cp[rowl*193 + col] = acc[i][j][r];
          }
        }
    }
    __syncthreads();
    {
      const int rowl = tid >> 2, grp = tid & 3;
      const int m = m0 + h*128 + rowl;
      const int g = by*4 + grp;
      const int s2 = g / Hn;                   // constant per block
      const float* crow = Cp + rowl*193 + grp*48;
      const float* ob   = obs + ((size_t)m*Sn + s2)*On;
      const float* bi   = ext + grp*48;
      const float* em   = ext + 192 + grp*48;
      float Z = 0.f, pd = 0.f, eo = 0.f;
#pragma unroll
      for (int o = 0; o < On; ++o){
        float e = __expf(crow[o] + bi[o]);
        float obv = ob[o];
        Z += e;
        pd = fmaf(e, obv, pd);
        eo = fmaf(em[o], obv, eo);
      }
      ws[OFF_LEPP + (size_t)m*Gn + g] = __logf((1.f-EMISS_W)*eo + EMISS_W*(pd/Z));
    }
  }
}

// ---------------- forward/backward recursions: chunked with warm-up ----------
// Serial depth 40 (FBW warm-up + FBL chunk). Stages exp(sum of 4 lep
// partials) straight from OFF_LEPP (lep_reduce kernel deleted).
constexpr int FBW = 24;   // warm-up steps
constexpr int FBL = 16;   // chunk length

__global__ __launch_bounds__(64) void fb_kernel(float* __restrict__ ws){
  __shared__ __align__(16) float ldsE[(FBW+FBL)*48];   // exp(lep) window
  __shared__ __align__(16) float ring[2][64];
  const int lane = threadIdx.x;
  const int c    = blockIdx.x;
  const int b    = blockIdx.y;
  const bool fwd = blockIdx.z == 0;
  const bool act = lane < Hn;
  const int t0 = c*FBL, te = t0 + FBL - 1;

  float pt[Hn];
#pragma unroll
  for (int i = 0; i < Hn; ++i)
    pt[i] = act ? (fwd ? ws[OFF_PT + i*Hn + lane] : ws[OFF_PT + lane*Hn + i]) : 0.f;

  int row_lo, nrows, sA, sZ;
  bool exact;
  if (fwd){
    sA = t0 - FBW;
    exact = (sA < 1);
    row_lo = exact ? 0 : sA;
    if (exact) sA = 1;
    sZ = te;
    nrows = te - row_lo + 1;
  } else {
    int th = te + 1 + FBW;
    exact = (th > Tn - 2);
    sA = exact ? Tn - 2 : th - 1;
    sZ = t0;
    row_lo = t0;
    nrows = sA - t0 + 1;
  }

  // stage exp(lep) = exp(sum of 4 partials) from [m][192] layout
  {
    const float* src = ws + OFF_LEPP + ((size_t)b*Tn + row_lo)*Gn;
    int n4 = nrows * (Hn/4);
    for (int i = lane; i < n4; i += 64){
      int r = i / (Hn/4), h4 = i - r*(Hn/4);
      const float* p = src + (size_t)r*Gn + h4*4;
      float4 a = *(const float4*)(p);
      float4 b2 = *(const float4*)(p + Hn);
      float4 c2 = *(const float4*)(p + 2*Hn);
      float4 d2 = *(const float4*)(p + 3*Hn);
      float4 e;
      e.x = __expf(a.x + b2.x + c2.x + d2.x);
      e.y = __expf(a.y + b2.y + c2.y + d2.y);
      e.z = __expf(a.z + b2.z + c2.z + d2.z);
      e.w = __expf(a.w + b2.w + c2.w + d2.w);
      ((float4*)ldsE)[i] = e;
    }
  }
  __syncthreads();

  if (fwd){
    const size_t laF = OFF_LA + (size_t)b * Tn * Hn;
    float v;
    if (exact){
      v = act ? __expf(ws[OFF_LP + lane]) * ldsE[lane] : 0.f;   // alpha_0
      if (c == 0 && act) ws[laF + lane] = v;
    } else {
      v = act ? 1.f : 0.f;
    }
    if (act) ring[0][lane] = v;
    __syncthreads();
    int cur = 0;
    for (int t = sA; t <= sZ; ++t){
      float S = waveSum(v);
      const float* rp = ring[cur];
      float s0=0.f,s1=0.f,s2=0.f,s3=0.f;
#pragma unroll
      for (int i = 0; i < Hn; i += 4){
        float4 a = *(const float4*)(rp + i);
        s0 = fmaf(a.x, pt[i+0], s0); s1 = fmaf(a.y, pt[i+1], s1);
        s2 = fmaf(a.z, pt[i+2], s2); s3 = fmaf(a.w, pt[i+3], s3);
      }
      float sd = (s0+s1)+(s2+s3);
      float e = act ? ldsE[(t - row_lo)*Hn + lane] : 0.f;
      float vn = act ? e * sd * (1.f/S) : 0.f;
      cur ^= 1;
      if (act) ring[cur][lane] = vn;
      __syncthreads();
      if (act && t >= t0) ws[laF + (size_t)t*Hn + lane] = vn;
      v = vn;
    }
  } else {
    const size_t lbF = OFF_LB + (size_t)b * Tn * Hn;
    float v = act ? 1.f : 0.f;
    if (exact && c == (Tn/FBL - 1) && act) ws[lbF + (size_t)(Tn-1)*Hn + lane] = 1.f;
    int cur = 0;
    for (int t = sA; t >= sZ; --t){
      float e = act ? ldsE[(t - row_lo)*Hn + lane] : 0.f;
      float wv = e * v;
      if (act) ring[cur][lane] = wv;
      float S = waveSum(wv);
      __syncthreads();
      const float* rp = ring[cur];
      float s0=0.f,s1=0.f,s2=0.f,s3=0.f;
#pragma unroll
      for (int j = 0; j < Hn; j += 4){
        float4 a = *(const float4*)(rp + j);
        s0 = fmaf(a.x, pt[j+0], s0); s1 = fmaf(a.y, pt[j+1], s1);
        s2 = fmaf(a.z, pt[j+2], s2); s3 = fmaf(a.w, pt[j+3], s3);
      }
      float vn = act ? ((s0+s1)+(s2+s3)) * (1.f/S) : 0.f;
      cur ^= 1;
      if (act && t <= te) ws[lbF + (size_t)t*Hn + lane] = vn;
      v = vn;
    }
  }
}

// -------- gamma / xi / masked accumulation (prob domain, no atomics) -----------
// One coalesced partial store per block; sum_kernel reduces. (R9's last-block
// counter pattern = 8192 serialized same-address atomics+fences = 165us. Never
// funnel per-block completion through one address on this chip.)
__global__ __launch_bounds__(256) void gamma_xi_kernel(
    const float* __restrict__ ws_c, float* __restrict__ ws,
    const int* __restrict__ seq_len){
  __shared__ float y_s[Hn], lap_s[Hn];
  __shared__ float red[8];
  const int tid = threadIdx.x;
  const int bid = blockIdx.x;
  const int b = bid >> 9, t = bid & (Tn-1);
  const int len = seq_len[b];
  int tb = t + (Tn - len); if (tb >= Tn) tb -= Tn;
  const size_t bt = (size_t)b*Tn + t;
  float lep = 0.f;
  if (tid < Hn){
    const float* lpp = ws_c + OFF_LEPP + bt*Gn + tid;
    lep = lpp[0] + lpp[Hn] + lpp[2*Hn] + lpp[3*Hn];
    float lb  = ws_c[OFF_LB + ((size_t)b*Tn + tb)*Hn + tid];
    y_s[tid] = __expf(lep) * lb;
    if (t >= 1) lap_s[tid] = ws_c[OFF_LA + (bt-1)*Hn + tid];
  }
  float emis_term = 0.f, prior_term = 0.f;
  if (tid < 64){
    int h = (tid < Hn) ? tid : 0;
    float la  = ws_c[OFF_LA + bt*Hn + h];
    float lb  = ws_c[OFF_LB + ((size_t)b*Tn + tb)*Hn + h];
    float lp  = ws_c[OFF_LP + h];
    float wgt = (tid < Hn) ? la*lb : 0.f;
    float Z = waveSum(wgt);
    float inv = 1.f / Z;
    emis_term  = waveSum(wgt * lep) * inv;
    prior_term = waveSum(wgt * lp) * inv;
  }
  __syncthreads();
  float tran_term = 0.f;
  if (t >= 1){
    float se = 0.f, st = 0.f;
#pragma unroll
    for (int k=0;k<9;++k){
      int e = tid + k*256;
      int i = e / Hn, j = e - i*Hn;
      float e2 = ws_c[OFF_PT + e] * lap_s[i] * y_s[j];
      se += e2;
      st = fmaf(e2, ws_c[OFF_LT + e], st);
    }
    se = waveSum(se);
    st = waveSum(st);
    const int wid = tid >> 6;
    if ((tid & 63) == 0){ red[wid] = se; red[4+wid] = st; }
    __syncthreads();
    if (tid == 0){
      float SE = red[0]+red[1]+red[2]+red[3];
      float ST = red[4]+red[5]+red[6]+red[7];
      tran_term = ST / SE;
    }
  }
  if (tid == 0){
    float tot = 0.f;
    if (t < len)            tot += emis_term;
    if (t == 0)             tot += prior_term;
    if (t >= 1 && t < len)  tot += tran_term;
    ws[OFF_RED + bid] = tot;
  }
}

// ---------------- final reduction: 8192 partials -> scalar ---------------------
__global__ __launch_bounds__(256) void sum_kernel(const float* __restrict__ ws,
                                                  float* __restrict__ out){
  __shared__ float red[4];
  const int tid = threadIdx.x;
  float s = 0.f;
  for (int i = tid; i < Mn; i += 256) s += ws[OFF_RED + i];
  s = waveSum(s);
  if ((tid & 63) == 0) red[tid >> 6] = s;
  __syncthreads();
  if (tid == 0) out[0] = (red[0]+red[1]+red[2]+red[3]) * (1.f / Bn);
}

} // namespace

extern "C" void kernel_launch(void* const* d_in, const int* in_sizes, int n_in,
                              void* d_out, int out_size, void* d_ws, size_t ws_size,
                              hipStream_t stream){
  const float* emb = (const float*)d_in[0];
  const float* obs = (const float*)d_in[1];
  const float* sp  = (const float*)d_in[2];
  const float* ut  = (const float*)d_in[3];
  const float* ue  = (const float*)d_in[4];
  const float* Wm  = (const float*)d_in[5];
  const float* bm  = (const float*)d_in[6];
  const int*   sl  = (const int*)d_in[7];
  float* ws  = (float*)d_ws;
  float* out = (float*)d_out;
  (void)in_sizes; (void)n_in; (void)ws_size; (void)out_size;

  unsigned short* embB = (unsigned short*)(ws + FLOATS_END);
  unsigned short* WB   = embB + (size_t)Mn * Dn;

  const int n4a = Mn*Dn/4, n4b = Nn*Dn/4;
  const int nconv = (n4a + n4b + 255)/256;
  convprep_kernel<<<nconv + 1, 256, 0, stream>>>(emb, embB, n4a, Wm, WB, n4b,
                                                 sp, ut, ue, ws, nconv);
  gemm_lep_kernel<<<dim3(Mn/BM, Nn/BN), 512, 0, stream>>>(embB, WB, bm, obs, ws);
  fb_kernel<<<dim3(Tn/FBL, Bn, 2), 64, 0, stream>>>(ws);
  gamma_xi_kernel<<<Bn*Tn, 256, 0, stream>>>(ws, ws, sl);
  sum_kernel<<<1, 256, 0, stream>>>(ws, out);
}